// Round 8
// baseline (6163.630 us; speedup 1.0000x reference)
//
#include <hip/hip_runtime.h>

// 2-layer LSTM encoder, v8: one CU per layer per sequence, pipelined via a
// global-memory ring.
//
// ROUND-7 FINDING: v5 (best, 600ns/step) is ~half issue-bound (~443 VALU
// cyc/wave/step, 2 waves/SIMD) and ~half DS-pipe/latency -- BOTH layers share
// one CU's DS pipe + SIMDs. v7 showed concentrating work in fewer waves makes
// it worse. v8 splits the layers onto DIFFERENT CUs:
//   blocks 0..63   : layer 1 of batch b (4 waves, v5 lane map, 1 barrier/step)
//   blocks 64..127 : layer 2 of batch b-64 (4 waves, 2 lanes/gate)
// l1 -> l2 hand-off: h1 ring in d_ws (64 steps deep) + producer/consumer
// flags, chunked every 8 steps (threadfence + release/acquire atomics, works
// across XCDs). l2 lags 8-24 steps; ring reads are register-prefetched one
// step ahead so the cross-CU latency is fully hidden.
// Flags are zeroed by hipMemsetAsync before launch (d_ws is poisoned 0xAA).

#define BATCH 64
#define T 4096
#define H1 64
#define H2 32
#define RSTEPS 64                    // ring depth (steps)
#define RING_BYTES ((size_t)BATCH * RSTEPS * H1 * 4)   // 1 MiB
#define L2E 1.442695040888963f

__device__ __forceinline__ float fast_rcp(float v){ return __builtin_amdgcn_rcpf(v); }

__global__ __launch_bounds__(256)
__attribute__((amdgpu_waves_per_eu(1, 1)))
void lstm2_v8(const float* __restrict__ x,
              const float* __restrict__ W_ih1, const float* __restrict__ W_hh1,
              const float* __restrict__ b_ih1, const float* __restrict__ b_hh1,
              const float* __restrict__ W_ih2, const float* __restrict__ W_hh2,
              const float* __restrict__ b_ih2, const float* __restrict__ b_hh2,
              float* __restrict__ out,
              float* __restrict__ ring, int* __restrict__ prod, int* __restrict__ cons)
{
    const int blk = blockIdx.x;
    const int tid = threadIdx.x;
    const int w = tid >> 6, lane = tid & 63;
    const int t = lane >> 4;               // gate type 0=i 1=f 2=g 3=o
    // act = sc_out * rcp(1 + exp2(sc_in2*s)) + sc_off  (sigmoid / tanh)
    const float sc_in2 = (t == 2) ? -2.0f * L2E : -L2E;
    const float sc_out = (t == 2) ?  2.0f : 1.0f;
    const float sc_off = (t == 2) ? -1.0f : 0.0f;

    if (blk < BATCH) {
        // ======================= LAYER 1 (producer) =======================
        const int b = blk;
        __shared__ __align__(16) float h1buf[2][H1];
        if (tid < 2 * H1) ((float*)h1buf)[tid] = 0.0f;

        const int base = lane & 15;
        const int j = 16 * w + base;       // unit
        const int g = 64 * t + j;          // gate row
        float4 wh0,wh1,wh2,wh3,wh4,wh5,wh6,wh7,wh8,wh9,wh10,wh11,wh12,wh13,wh14,wh15;
        {
            const float4* r = (const float4*)(W_hh1 + (size_t)g * H1);
            wh0=r[0]; wh1=r[1]; wh2=r[2]; wh3=r[3]; wh4=r[4]; wh5=r[5]; wh6=r[6]; wh7=r[7];
            wh8=r[8]; wh9=r[9]; wh10=r[10]; wh11=r[11]; wh12=r[12]; wh13=r[13]; wh14=r[14]; wh15=r[15];
        }
        const float4 wx = *(const float4*)(W_ih1 + (size_t)g * 4);
        const float bias = b_ih1[g] + b_hh1[g];
        float c1 = 0.0f;
        const float4* xptr = (const float4*)(x + (size_t)b * T * 4);
        float4 xc = xptr[0];
        float* ringb = ring + (size_t)b * RSTEPS * H1;
        int* prodb = prod + b * 16;
        int* consb = cons + b * 16;
        __syncthreads();

#define L1FMA(W,H) do{ a0=fmaf((H).x,(W).x,a0); a1=fmaf((H).y,(W).y,a1); \
                       a2=fmaf((H).z,(W).z,a2); a3=fmaf((H).w,(W).w,a3);}while(0)
        for (int n = 0; n < T; ++n) {
            if ((n & 15) == 0 && n >= 48) {        // ring backpressure
                while (__hip_atomic_load(consb, __ATOMIC_RELAXED, __HIP_MEMORY_SCOPE_AGENT) < n - 40)
                    __builtin_amdgcn_s_sleep(8);
            }
            float4 xn = xptr[(n + 1 < T) ? (n + 1) : (T - 1)];
            float a0 = bias, a1 = 0.f, a2 = 0.f, a3 = 0.f;
            a0 = fmaf(xc.x, wx.x, a0); a1 = fmaf(xc.y, wx.y, a1);
            a2 = fmaf(xc.z, wx.z, a2); a3 = fmaf(xc.w, wx.w, a3);
            const float4* hv = (const float4*)h1buf[(n + 1) & 1];  // h1(n-1)
            float4 h;
            h=hv[0]; L1FMA(wh0,h);  h=hv[1]; L1FMA(wh1,h);  h=hv[2]; L1FMA(wh2,h);  h=hv[3]; L1FMA(wh3,h);
            h=hv[4]; L1FMA(wh4,h);  h=hv[5]; L1FMA(wh5,h);  h=hv[6]; L1FMA(wh6,h);  h=hv[7]; L1FMA(wh7,h);
            h=hv[8]; L1FMA(wh8,h);  h=hv[9]; L1FMA(wh9,h);  h=hv[10];L1FMA(wh10,h); h=hv[11];L1FMA(wh11,h);
            h=hv[12];L1FMA(wh12,h); h=hv[13];L1FMA(wh13,h); h=hv[14];L1FMA(wh14,h); h=hv[15];L1FMA(wh15,h);
            float acc = (a0 + a1) + (a2 + a3);
            float act = fmaf(sc_out, fast_rcp(1.0f + exp2f(sc_in2 * acc)), sc_off);
            float gi = __shfl(act, base,      64);
            float gf = __shfl(act, base + 16, 64);
            float gg = __shfl(act, base + 32, 64);
            float go = __shfl(act, base + 48, 64);
            c1 = fmaf(gf, c1, gi * gg);
            float hn = go * (1.0f - 2.0f * fast_rcp(exp2f(2.0f * L2E * c1) + 1.0f));
            if (t == 0) {
                h1buf[n & 1][j] = hn;
                ringb[(size_t)(n & (RSTEPS - 1)) * H1 + j] = hn;
            }
            xc = xn;
            if ((n & 7) == 7) {                    // publish chunk
                __threadfence();                   // all waves drain+wb
                __syncthreads();
                if (tid == 0)
                    __hip_atomic_store(prodb, n + 1, __ATOMIC_RELEASE, __HIP_MEMORY_SCOPE_AGENT);
            } else {
                __syncthreads();
            }
        }
#undef L1FMA
    } else {
        // ======================= LAYER 2 (consumer) =======================
        const int b = blk - BATCH;
        __shared__ __align__(16) float h2buf[2][H2];
        if (tid < 2 * H2) ((float*)h2buf)[tid] = 0.0f;

        const int pos = lane & 15;
        const int u = pos >> 1, half = lane & 1;
        const int j = 8 * w + u;           // unit
        const int g = 32 * t + j;          // gate row
        // K split: half0 -> h1[0..48); half1 -> h1[48..64) + h2[0..32)
        float4 wk0,wk1,wk2,wk3,wk4,wk5,wk6,wk7,wk8,wk9,wk10,wk11;
        float bias;
        if (half == 0) {
            const float4* r = (const float4*)(W_ih2 + (size_t)g * H1);
            wk0=r[0]; wk1=r[1]; wk2=r[2]; wk3=r[3]; wk4=r[4]; wk5=r[5];
            wk6=r[6]; wk7=r[7]; wk8=r[8]; wk9=r[9]; wk10=r[10]; wk11=r[11];
            bias = b_ih2[g] + b_hh2[g];
        } else {
            const float4* r = (const float4*)(W_ih2 + (size_t)g * H1) + 12;
            wk0=r[0]; wk1=r[1]; wk2=r[2]; wk3=r[3];
            const float4* r2 = (const float4*)(W_hh2 + (size_t)g * H2);
            wk4=r2[0]; wk5=r2[1]; wk6=r2[2]; wk7=r2[3];
            wk8=r2[4]; wk9=r2[5]; wk10=r2[6]; wk11=r2[7];
            bias = 0.0f;
        }
        float c2 = 0.0f;
        float* outb = out + (size_t)b * T * H2;
        const float* ringb = ring + (size_t)b * RSTEPS * H1;
        int* prodb = prod + b * 16;
        int* consb = cons + b * 16;
        __syncthreads();

        // gate chunk 0: need h1 through step 15
        {
            int need = (16 < T) ? 16 : T;
            while (__hip_atomic_load(prodb, __ATOMIC_RELAXED, __HIP_MEMORY_SCOPE_AGENT) < need)
                __builtin_amdgcn_s_sleep(8);
            __threadfence();                       // acquire
        }
        float4 cg0,cg1,cg2,cg3,cg4,cg5,cg6,cg7,cg8,cg9,cg10,cg11;
        {
            const float4* rs = (const float4*)ringb;   // slot 0 = h1(0)
            if (half == 0) {
                cg0=rs[0]; cg1=rs[1]; cg2=rs[2]; cg3=rs[3]; cg4=rs[4]; cg5=rs[5];
                cg6=rs[6]; cg7=rs[7]; cg8=rs[8]; cg9=rs[9]; cg10=rs[10]; cg11=rs[11];
            } else {
                cg0=rs[12]; cg1=rs[13]; cg2=rs[14]; cg3=rs[15];
            }
        }

#define L2FMA(W,H) do{ a0=fmaf((H).x,(W).x,a0); a1=fmaf((H).y,(W).y,a1); \
                       a2=fmaf((H).z,(W).z,a2); a3=fmaf((H).w,(W).w,a3);}while(0)
        for (int m = 0; m < T; ++m) {
            // prefetch h1(m+1) slice (covered by current chunk's gate)
            float4 ng0,ng1,ng2,ng3,ng4,ng5,ng6,ng7,ng8,ng9,ng10,ng11;
            if (m + 1 < T) {
                const float4* rs = (const float4*)(ringb + (size_t)((m + 1) & (RSTEPS - 1)) * H1);
                if (half == 0) {
                    ng0=rs[0]; ng1=rs[1]; ng2=rs[2]; ng3=rs[3]; ng4=rs[4]; ng5=rs[5];
                    ng6=rs[6]; ng7=rs[7]; ng8=rs[8]; ng9=rs[9]; ng10=rs[10]; ng11=rs[11];
                } else {
                    ng0=rs[12]; ng1=rs[13]; ng2=rs[14]; ng3=rs[15];
                }
            }
            if (half == 1) {                       // h2(m-1) from LDS
                const float4* h2v = (const float4*)h2buf[(m + 1) & 1];
                cg4=h2v[0]; cg5=h2v[1]; cg6=h2v[2]; cg7=h2v[3];
                cg8=h2v[4]; cg9=h2v[5]; cg10=h2v[6]; cg11=h2v[7];
            }
            float a0 = bias, a1 = 0.f, a2 = 0.f, a3 = 0.f;
            L2FMA(wk0,cg0); L2FMA(wk1,cg1); L2FMA(wk2,cg2);  L2FMA(wk3,cg3);
            L2FMA(wk4,cg4); L2FMA(wk5,cg5); L2FMA(wk6,cg6);  L2FMA(wk7,cg7);
            L2FMA(wk8,cg8); L2FMA(wk9,cg9); L2FMA(wk10,cg10);L2FMA(wk11,cg11);
            float part = (a0 + a1) + (a2 + a3);
            float acc = part + __shfl_xor(part, 1, 64);
            float act = fmaf(sc_out, fast_rcp(1.0f + exp2f(sc_in2 * acc)), sc_off);
            float gi = __shfl(act, pos,      64);
            float gf = __shfl(act, pos + 16, 64);
            float gg = __shfl(act, pos + 32, 64);
            float go = __shfl(act, pos + 48, 64);
            c2 = fmaf(gf, c2, gi * gg);
            float h = go * (1.0f - 2.0f * fast_rcp(exp2f(2.0f * L2E * c2) + 1.0f));
            if (t == 0 && half == 0) {
                h2buf[m & 1][j] = h;
                outb[(size_t)m * H2 + j] = h;
            }
            // rotate prefetch into current
            cg0=ng0; cg1=ng1; cg2=ng2; cg3=ng3;
            if (half == 0) { cg4=ng4; cg5=ng5; cg6=ng6; cg7=ng7; cg8=ng8; cg9=ng9; cg10=ng10; cg11=ng11; }
            if ((m & 7) == 7 && m + 1 < T) {       // chunk boundary
                if (tid == 0)
                    __hip_atomic_store(consb, m + 1, __ATOMIC_RELAXED, __HIP_MEMORY_SCOPE_AGENT);
                int need = m + 17; if (need > T) need = T;
                while (__hip_atomic_load(prodb, __ATOMIC_RELAXED, __HIP_MEMORY_SCOPE_AGENT) < need)
                    __builtin_amdgcn_s_sleep(8);
                __threadfence();                   // acquire for next chunk
            }
            __syncthreads();                       // h2buf phase separation
        }
#undef L2FMA
    }
}

extern "C" void kernel_launch(void* const* d_in, const int* in_sizes, int n_in,
                              void* d_out, int out_size, void* d_ws, size_t ws_size,
                              hipStream_t stream) {
    const float* x     = (const float*)d_in[0];
    const float* W_ih1 = (const float*)d_in[1];
    const float* W_hh1 = (const float*)d_in[2];
    const float* b_ih1 = (const float*)d_in[3];
    const float* b_hh1 = (const float*)d_in[4];
    const float* W_ih2 = (const float*)d_in[5];
    const float* W_hh2 = (const float*)d_in[6];
    const float* b_ih2 = (const float*)d_in[7];
    const float* b_hh2 = (const float*)d_in[8];
    float* out = (float*)d_out;

    float* ring = (float*)d_ws;
    int*   prod = (int*)((char*)d_ws + RING_BYTES);           // 64 x 64B
    int*   cons = (int*)((char*)d_ws + RING_BYTES + 4096);    // 64 x 64B
    // flags must start at 0 (d_ws is poisoned before every timed launch)
    hipMemsetAsync((char*)d_ws + RING_BYTES, 0, 8192, stream);

    lstm2_v8<<<dim3(2 * BATCH), dim3(256), 0, stream>>>(
        x, W_ih1, W_hh1, b_ih1, b_hh1, W_ih2, W_hh2, b_ih2, b_hh2, out,
        ring, prod, cons);
}

// Round 9
// 2750.462 us; speedup vs baseline: 2.2409x; 2.2409x over previous
//
#include <hip/hip_runtime.h>

// 2-layer LSTM encoder, v9 = v5 + drain-free barriers + batched output store.
//
// ROUND-8 FINDING: cross-CU pipelining (v8) regressed badly; v5 remains best.
// v5's residual per-step cost: __syncthreads() compiles to
// `s_waitcnt vmcnt(0) lgkmcnt(0); s_barrier`, and layer-2 issues a global
// store of `out` EVERY step -> every barrier waits an HBM store retire
// (~300-600 cyc) on the recurrence's critical path.
// v9: (a) out goes to an LDS tile, flushed coalesced once per 32 steps;
//     (b) in-loop barrier = raw `s_waitcnt lgkmcnt(0); s_barrier` (LDS
//         visibility only -- vmem never force-drained in the loop).
//
// Structure (= v5): 64 blocks (1/batch), 512 threads = 8 waves.
//   waves 0..3: layer-1, 16 units/wave, lane = 16*type + unit. 68 FMA/lane.
//   waves 4..7: layer-2, 8 units/wave, lane = 16*type + 2*unit + half,
//               48 FMA/lane, halves combined via shfl_xor(.,1).
//   Iter n = l1 step n + l2 step n-1, both read h1(n-1); 1 barrier/step;
//   gates gathered by intra-wave shuffles; weights in named-float4 regs
//   (amdgpu_waves_per_eu(2,2) -> 256-VGPR budget, stays resident);
//   x staged via 2-chunk LDS ring (1 global load / 64 steps).

#define BATCH 64
#define T 4096
#define IN_DIM 4
#define H1 64
#define H2 32
#define NTHREADS 512
#define L2E 1.442695040888963f

__device__ __forceinline__ float fast_rcp(float v) { return __builtin_amdgcn_rcpf(v); }

// Barrier with LDS-only drain: does NOT wait vmcnt (unlike __syncthreads).
__device__ __forceinline__ void barrier_lgkm() {
    asm volatile("s_waitcnt lgkmcnt(0)" ::: "memory");
    __builtin_amdgcn_s_barrier();
}

__global__ __launch_bounds__(NTHREADS)
__attribute__((amdgpu_waves_per_eu(2, 2)))
void lstm2_v9(const float* __restrict__ x,
              const float* __restrict__ W_ih1, const float* __restrict__ W_hh1,
              const float* __restrict__ b_ih1, const float* __restrict__ b_hh1,
              const float* __restrict__ W_ih2, const float* __restrict__ W_hh2,
              const float* __restrict__ b_ih2, const float* __restrict__ b_hh2,
              float* __restrict__ out)
{
    const int b    = blockIdx.x;
    const int tid  = threadIdx.x;
    const int wave = tid >> 6;
    const int lane = tid & 63;
    const bool is_l1 = (wave < 4);
    const int type = lane >> 4;        // 0=i 1=f 2=g 3=o
    const int base = lane & 15;        // type-0 lane of my unit
    const int half = lane & 1;         // layer-2 dot-product half

    __shared__ __align__(16) float h1buf[2][H1];
    __shared__ __align__(16) float h2buf[2][H2];
    __shared__ __align__(16) float xbuf[2][64][IN_DIM];  // 2-chunk x ring
    __shared__ __align__(16) float obuf[2][32][H2];      // out staging tiles

    if (tid < 2 * H1)                    ((float*)h1buf)[tid] = 0.0f;
    else if (tid < 2 * H1 + 2 * H2)      ((float*)h2buf)[tid - 2 * H1] = 0.0f;

    // act = sc_out * rcp(1 + exp2(sc_in2*acc)) + sc_off
    const float sc_in2 = (type == 2) ? -2.0f * L2E : -L2E;
    const float sc_out = (type == 2) ?  2.0f :  1.0f;
    const float sc_off = (type == 2) ? -1.0f :  0.0f;

    float4 wh0, wh1, wh2, wh3, wh4, wh5, wh6, wh7;
    float4 wh8, wh9, wh10, wh11, wh12, wh13, wh14, wh15;
    float4 wx = make_float4(0.f, 0.f, 0.f, 0.f);
    float bias;
    int   j;
    float c = 0.0f;

    if (is_l1) {
        j = 16 * wave + base;
        const int g = type * H1 + j;
        const float4* wr = (const float4*)(W_hh1 + (size_t)g * H1);
        wh0  = wr[0];  wh1  = wr[1];  wh2  = wr[2];  wh3  = wr[3];
        wh4  = wr[4];  wh5  = wr[5];  wh6  = wr[6];  wh7  = wr[7];
        wh8  = wr[8];  wh9  = wr[9];  wh10 = wr[10]; wh11 = wr[11];
        wh12 = wr[12]; wh13 = wr[13]; wh14 = wr[14]; wh15 = wr[15];
        wx = *(const float4*)(W_ih1 + (size_t)g * IN_DIM);
        bias = b_ih1[g] + b_hh1[g];
    } else {
        j = 8 * (wave - 4) + (base >> 1);
        const int g = type * H2 + j;
        const float4* wi = (const float4*)(W_ih2 + (size_t)g * H1) + (half << 3);
        wh0 = wi[0]; wh1 = wi[1]; wh2 = wi[2]; wh3 = wi[3];
        wh4 = wi[4]; wh5 = wi[5]; wh6 = wi[6]; wh7 = wi[7];
        const float4* wp = (const float4*)(W_hh2 + (size_t)g * H2) + (half << 2);
        wh8 = wp[0]; wh9 = wp[1]; wh10 = wp[2]; wh11 = wp[3];
        wh12 = wh13 = wh14 = wh15 = make_float4(0.f, 0.f, 0.f, 0.f);
        bias = half ? 0.0f : (b_ih2[g] + b_hh2[g]);   // only half 0 carries bias
    }

    const float4* xptr = (const float4*)(x + (size_t)b * T * IN_DIM);
    float4 xg = make_float4(0.f, 0.f, 0.f, 0.f);
    if (wave == 0) {
        float4 x0 = xptr[lane];                       // chunk 0
        *(float4*)&xbuf[0][lane][0] = x0;
        xg = xptr[64 + lane];                         // chunk 1 in flight
    }
    float* const outb = out + (size_t)b * T * H2;

    __syncthreads();   // full barrier once (init)

#define FMA4(W, HH) do { a0 = fmaf((HH).x, (W).x, a0); a1 = fmaf((HH).y, (W).y, a1); \
                         a2 = fmaf((HH).z, (W).z, a2); a3 = fmaf((HH).w, (W).w, a3); } while (0)

    for (int n = 0; n <= T; ++n) {
        // ---- flush a sealed 32-step out tile (all threads, coalesced) ----
        // At top of iter n, outputs m <= n-2 are sealed. Fire when the tile
        // m0..m0+31 (m0 = n-33) completed: n >= 33 && n % 32 == 1.
        if (n >= 33 && (n & 31) == 1) {
            const int m0 = n - 33;
            const float* src = &obuf[(m0 >> 5) & 1][0][0];
            float2 vv = *(const float2*)(src + 2 * tid);
            *(float2*)(outb + (size_t)m0 * H2 + 2 * tid) = vv;
        }

        if (is_l1) {
            if (n < T) {
                const int s = n & 63, cch = n >> 6;
                if (s == 0 && wave == 0) {
                    *(float4*)&xbuf[(cch + 1) & 1][lane][0] = xg;   // publish next chunk
                    const int nb = (cch + 2) << 6;
                    if (nb < T) xg = xptr[nb + lane];               // prefetch
                }
                float a0 = bias, a1 = 0.f, a2 = 0.f, a3 = 0.f;
                const float4* hv = (const float4*)h1buf[(n + 1) & 1];   // h1(n-1)
                float4 hh;
                hh = hv[0];  FMA4(wh0,  hh);
                hh = hv[1];  FMA4(wh1,  hh);
                hh = hv[2];  FMA4(wh2,  hh);
                hh = hv[3];  FMA4(wh3,  hh);
                hh = hv[4];  FMA4(wh4,  hh);
                hh = hv[5];  FMA4(wh5,  hh);
                hh = hv[6];  FMA4(wh6,  hh);
                hh = hv[7];  FMA4(wh7,  hh);
                hh = hv[8];  FMA4(wh8,  hh);
                hh = hv[9];  FMA4(wh9,  hh);
                hh = hv[10]; FMA4(wh10, hh);
                hh = hv[11]; FMA4(wh11, hh);
                hh = hv[12]; FMA4(wh12, hh);
                hh = hv[13]; FMA4(wh13, hh);
                hh = hv[14]; FMA4(wh14, hh);
                hh = hv[15]; FMA4(wh15, hh);
                float4 xt = *(const float4*)&xbuf[cch & 1][s][0];       // broadcast
                FMA4(wx, xt);
                float acc = (a0 + a1) + (a2 + a3);
                float act = fmaf(sc_out, fast_rcp(1.0f + exp2f(sc_in2 * acc)), sc_off);
                float gi = __shfl(act, base,      64);
                float gf = __shfl(act, base + 16, 64);
                float gg = __shfl(act, base + 32, 64);
                float go = __shfl(act, base + 48, 64);
                c = fmaf(gf, c, gi * gg);
                float th = 1.0f - 2.0f * fast_rcp(exp2f(2.0f * L2E * c) + 1.0f);
                float h = go * th;
                if (lane < 16) h1buf[n & 1][j] = h;
            }
        } else {
            if (n >= 1) {
                float a0 = bias, a1 = 0.f, a2 = 0.f, a3 = 0.f;
                const float4* hv = (const float4*)h1buf[(n + 1) & 1] + (half << 3); // h1(n-1)
                float4 hh;
                hh = hv[0]; FMA4(wh0, hh);
                hh = hv[1]; FMA4(wh1, hh);
                hh = hv[2]; FMA4(wh2, hh);
                hh = hv[3]; FMA4(wh3, hh);
                hh = hv[4]; FMA4(wh4, hh);
                hh = hv[5]; FMA4(wh5, hh);
                hh = hv[6]; FMA4(wh6, hh);
                hh = hv[7]; FMA4(wh7, hh);
                const float4* h2v = (const float4*)h2buf[n & 1] + (half << 2);      // h2(n-2)
                hh = h2v[0]; FMA4(wh8,  hh);
                hh = h2v[1]; FMA4(wh9,  hh);
                hh = h2v[2]; FMA4(wh10, hh);
                hh = h2v[3]; FMA4(wh11, hh);
                float part = (a0 + a1) + (a2 + a3);
                float acc = part + __shfl_xor(part, 1, 64);   // combine lane pair
                float act = fmaf(sc_out, fast_rcp(1.0f + exp2f(sc_in2 * acc)), sc_off);
                float gi = __shfl(act, base,      64);
                float gf = __shfl(act, base + 16, 64);
                float gg = __shfl(act, base + 32, 64);
                float go = __shfl(act, base + 48, 64);
                c = fmaf(gf, c, gi * gg);
                float th = 1.0f - 2.0f * fast_rcp(exp2f(2.0f * L2E * c) + 1.0f);
                float h = go * th;
                if ((lane & 49) == 0) {            // type==0 && half==0
                    const int m = n - 1;
                    h2buf[(n + 1) & 1][j] = h;
                    obuf[(m >> 5) & 1][m & 31][j] = h;   // staged, not global
                }
            }
        }
        barrier_lgkm();
    }

    // ---- tail flush: last tile m = T-32 .. T-1 (sealed by final barrier) ----
    {
        const int m0 = T - 32;
        const float* src = &obuf[(m0 >> 5) & 1][0][0];
        float2 vv = *(const float2*)(src + 2 * tid);
        *(float2*)(outb + (size_t)m0 * H2 + 2 * tid) = vv;
    }
#undef FMA4
}

extern "C" void kernel_launch(void* const* d_in, const int* in_sizes, int n_in,
                              void* d_out, int out_size, void* d_ws, size_t ws_size,
                              hipStream_t stream) {
    const float* x     = (const float*)d_in[0];
    const float* W_ih1 = (const float*)d_in[1];
    const float* W_hh1 = (const float*)d_in[2];
    const float* b_ih1 = (const float*)d_in[3];
    const float* b_hh1 = (const float*)d_in[4];
    const float* W_ih2 = (const float*)d_in[5];
    const float* W_hh2 = (const float*)d_in[6];
    const float* b_ih2 = (const float*)d_in[7];
    const float* b_hh2 = (const float*)d_in[8];
    float* out = (float*)d_out;

    lstm2_v9<<<dim3(BATCH), dim3(NTHREADS), 0, stream>>>(
        x, W_ih1, W_hh1, b_ih1, b_hh1, W_ih2, W_hh2, b_ih2, b_hh2, out);
}